// Round 5
// baseline (215.973 us; speedup 1.0000x reference)
//
#include <hip/hip_runtime.h>

// SSIM 3D loss: pred/target f32 [4,1,64,192,192], scalar 1 - mean(ssim_map).
// v15: v14 + BARRIER DRAIN FIX (T4 counted-vmcnt idea applied to a stencil):
//      __syncthreads() = s_waitcnt vmcnt(0) lgkmcnt(0) + s_barrier -> the 6
//      global prefetch loads issued right before sync1 were fully drained at
//      the barrier, exposing ~300-900 cyc of L3/HBM latency per plane
//      (VALUBusy stuck at ~60% across v12-v14). Replace loop barriers with
//      raw s_barrier + explicit lgkmcnt(0) ONLY: LDS ordering preserved
//      (stage/W writes + W/H reads are all lgkm), while vmcnt stays in
//      flight across barriers; compiler auto-waits vmcnt at the commit's
//      register use one full plane later (coverage ~900+ cyc).
//      Everything else identical to v14.

#define D_DIM 64
#define H_DIM 192
#define W_DIM 192
#define SLICE (H_DIM * W_DIM)   // 36864
#define VOL   (D_DIM * SLICE)   // 2359296
#define NB    4
#define KS    11
#define RAD   5
#define TIL   16                // output tile 16x16
#define HLO   26                // halo extent
#define SROWS 32                // padded stage rows (2 uniform W tasks/thread)
#define SP2   28                // float2 staging pitch
#define IPP   17                // interm pitch (elements) per row
#define C1F   (0.01f * 0.01f)
#define C2F   (0.03f * 0.03f)

// LDS-only barrier: order LDS ops, leave global loads (vmcnt) in flight.
#define BAR_LDS() do {                                                    \
    asm volatile("s_waitcnt lgkmcnt(0)" ::: "memory");                    \
    __builtin_amdgcn_s_barrier();                                         \
    __builtin_amdgcn_sched_barrier(0);                                    \
} while (0)

__device__ __forceinline__ void make_window(float* g) {
    float s = 0.f;
#pragma unroll
    for (int i = 0; i < KS; ++i) {
        float c = (float)(i - RAD);
        g[i] = expf(-(c * c) * (1.0f / 4.5f));  // 2*sigma^2 = 4.5
        s += g[i];
    }
    float inv = 1.0f / s;
#pragma unroll
    for (int i = 0; i < KS; ++i) g[i] *= inv;
}

#define SSIM_ACC(MP, MT, E2, T2, PT) do {                                 \
    float _mps = (MP) * (MP), _mts = (MT) * (MT), _mpt = (MP) * (MT);     \
    float _num = (2.f * _mpt + C1F) * (2.f * ((PT) - _mpt) + C2F);        \
    float _den = (_mps + _mts + C1F) *                                    \
                 (((E2) - _mps) + ((T2) - _mts) + C2F);                   \
    ssim_sum += _num * __builtin_amdgcn_rcpf(_den);                       \
} while (0)

__global__ __launch_bounds__(256) void fused_ssim_kernel(
    const float* __restrict__ pred, const float* __restrict__ targ,
    float* __restrict__ partials) {
    __shared__ float2 spt[SROWS * SP2];              // 7168 B
    __shared__ float2 i01[SROWS * IPP];              // 4352 B
    __shared__ float2 i23[SROWS * IPP];              // 4352 B
    __shared__ float  i4 [SROWS * IPP];              // 2176 B
    __shared__ float red[4];

    float g[KS];
    make_window(g);

    const int tid = threadIdx.x;
    const int h0 = (blockIdx.x / 12) * TIL;
    const int w0 = (blockIdx.x % 12) * TIL;
    const int half = blockIdx.y;
    const float* pb = pred + (size_t)blockIdx.z * VOL;
    const float* tb = targ + (size_t)blockIdx.z * VOL;
    const int q0 = half ? 27 : 0;                    // first plane
    const int q1 = half ? 63 : 36;                   // last plane (incl)
    const int d_lo = half ? 32 : 0;
    const int d_hi = half ? 63 : 31;

    // ---- zero pad rows 26..31 of stage (read by W, never written) ----
    for (int i = HLO * SP2 + tid; i < SROWS * SP2; i += 256)
        spt[i] = make_float2(0.f, 0.f);
    // (visibility to W ordered by the loop's first barrier)

    // ---- plane-invariant staging precompute (676 halo px, 3 strides) ----
    int sidx[3], slds[3];
    bool sa[3], sv[3];
#pragma unroll
    for (int k = 0; k < 3; ++k) {
        int i = tid + 256 * k;
        sa[k] = i < HLO * HLO;
        int y = i / HLO, x = i - y * HLO;
        int gh = h0 + y - RAD, gw = w0 + x - RAD;
        sv[k] = sa[k] && (unsigned)gh < (unsigned)H_DIM &&
                (unsigned)gw < (unsigned)W_DIM;
        sidx[k] = gh * W_DIM + gw;
        slds[k] = y * SP2 + x;
    }
    const int py = tid >> 4, px = tid & 15;          // H-phase pixel

    // ---- D-window accumulators: slot j = output d = q + j - 5 ----
    float a0[KS], a1[KS], a2[KS], a3[KS], a4[KS];
#pragma unroll
    for (int j = 0; j < KS; ++j)
        a0[j] = a1[j] = a2[j] = a3[j] = a4[j] = 0.f;
    float ssim_sum = 0.f;

    // prologue: load plane q0 into regs
    float rp[3], rt[3];
    {
        const float* pq = pb + q0 * SLICE;
        const float* tq = tb + q0 * SLICE;
#pragma unroll
        for (int k = 0; k < 3; ++k) {
            rp[k] = sv[k] ? pq[sidx[k]] : 0.f;
            rt[k] = sv[k] ? tq[sidx[k]] : 0.f;
        }
    }

    for (int q = q0;; ++q) {
        // commit staged regs -> LDS (vmcnt auto-wait lands here, one full
        // plane after issue; WAR vs W(q-1) ordered by barrier2(q-1))
#pragma unroll
        for (int k = 0; k < 3; ++k)
            if (sa[k]) spt[slds[k]] = make_float2(rp[k], rt[k]);
        // prefetch next plane; stays in flight across both barriers
        if (q < q1) {
            const float* pn = pb + (q + 1) * SLICE;
            const float* tn = tb + (q + 1) * SLICE;
#pragma unroll
            for (int k = 0; k < 3; ++k) {
                rp[k] = sv[k] ? pn[sidx[k]] : 0.f;
                rt[k] = sv[k] ? tn[sidx[k]] : 0.f;
            }
        }
        BAR_LDS();                                   // stage visible; H(q-1) done

        // ---- W phase: 512 uniform tasks (32 rows x 16 cols), f32 SoA out ----
#pragma unroll
        for (int it = 0; it < 2; ++it) {
            int t = tid + it * 256;                  // 0..511, all valid
            int r = t >> 4, c = t & 15;
            const float2* pr = spt + r * SP2 + c;
            float s0 = 0.f, s1 = 0.f, s2 = 0.f, s3 = 0.f, s4 = 0.f;
#pragma unroll
            for (int k = 0; k < KS; ++k) {
                float2 v = pr[k];                    // ds_read_b64
                float pv = v.x, tv = v.y, gk = g[k];
                s0 += gk * pv;
                s1 += gk * tv;
                s2 += gk * pv * pv;
                s3 += gk * tv * tv;
                s4 += gk * pv * tv;
            }
            int oi = r * IPP + c;
            i01[oi] = make_float2(s0, s1);           // ds_write_b64
            i23[oi] = make_float2(s2, s3);           // ds_write_b64
            i4 [oi] = s4;                            // ds_write_b32
        }
        BAR_LDS();                                   // interm visible

        // ---- H phase (zero cvt) + D accumulate + emit ----
        {
            const float2* c01 = i01 + px;
            const float2* c23 = i23 + px;
            const float*  c4  = i4  + px;
            float v0 = 0.f, v1 = 0.f, v2 = 0.f, v3 = 0.f, v4 = 0.f;
#pragma unroll
            for (int k = 0; k < KS; ++k) {
                int rr = (py + k) * IPP;
                float2 a = c01[rr];                  // ds_read_b64
                float2 b = c23[rr];                  // ds_read_b64
                float  e = c4[rr];                   // ds_read_b32
                float gk = g[k];
                v0 += gk * a.x;
                v1 += gk * a.y;
                v2 += gk * b.x;
                v3 += gk * b.y;
                v4 += gk * e;
            }
            // plane q contributes g[10-j] to output d = q + j - 5
#pragma unroll
            for (int j = 0; j < KS; ++j) {
                float wj = g[10 - j];
                a0[j] += wj * v0; a1[j] += wj * v1; a2[j] += wj * v2;
                a3[j] += wj * v3; a4[j] += wj * v4;
            }
            if (q - 5 >= d_lo)                       // d = q-5 complete
                SSIM_ACC(a0[0], a1[0], a2[0], a3[0], a4[0]);
            // shift window down (compile-time indices -> registers)
#pragma unroll
            for (int j = 0; j < KS - 1; ++j) {
                a0[j] = a0[j + 1]; a1[j] = a1[j + 1]; a2[j] = a2[j + 1];
                a3[j] = a3[j + 1]; a4[j] = a4[j + 1];
            }
            a0[10] = 0.f; a1[10] = 0.f; a2[10] = 0.f; a3[10] = 0.f; a4[10] = 0.f;
        }
        if (q == q1) break;
    }

    // ---- tail: outputs d = q1-4 .. q1 (zero-padded D windows) ----
#pragma unroll
    for (int j = 0; j < 5; ++j) {
        int d = q1 - 4 + j;
        if (d >= d_lo && d <= d_hi)
            SSIM_ACC(a0[j], a1[j], a2[j], a3[j], a4[j]);
    }

    // ---- block reduction ----
    float a = ssim_sum;
#pragma unroll
    for (int off = 32; off > 0; off >>= 1) a += __shfl_down(a, off, 64);
    int lane = tid & 63, wv = tid >> 6;
    if (lane == 0) red[wv] = a;
    __syncthreads();
    if (tid == 0)
        partials[((blockIdx.z * 2 + blockIdx.y) * 144) + blockIdx.x] =
            red[0] + red[1] + red[2] + red[3];
}

// ---- final reduction ----
__global__ __launch_bounds__(256) void finalize_kernel(
    const float* __restrict__ partials, int n, float* __restrict__ out) {
    double a = 0.0;
    for (int i = threadIdx.x; i < n; i += 256) a += (double)partials[i];
#pragma unroll
    for (int off = 32; off > 0; off >>= 1) a += __shfl_down(a, off, 64);
    __shared__ double red[4];
    int lane = threadIdx.x & 63, wv = threadIdx.x >> 6;
    if (lane == 0) red[wv] = a;
    __syncthreads();
    if (threadIdx.x == 0) {
        double s = red[0] + red[1] + red[2] + red[3];
        out[0] = (float)(1.0 - s / (double)((long long)NB * VOL));
    }
}

extern "C" void kernel_launch(void* const* d_in, const int* in_sizes, int n_in,
                              void* d_out, int out_size, void* d_ws, size_t ws_size,
                              hipStream_t stream) {
    const float* pred = (const float*)d_in[0];
    const float* targ = (const float*)d_in[1];
    float* out = (float*)d_out;
    float* partials = (float*)d_ws;                  // NB*288 floats

    fused_ssim_kernel<<<dim3(144, 2, NB), 256, 0, stream>>>(pred, targ, partials);
    finalize_kernel<<<1, 256, 0, stream>>>(partials, NB * 288, out);
}

// Round 6
// 203.269 us; speedup vs baseline: 1.0625x; 1.0625x over previous
//
#include <hip/hip_runtime.h>

// SSIM 3D loss: pred/target f32 [4,1,64,192,192], scalar 1 - mean(ssim_map).
// v16: v15 + PACKED-F32 math (v_pk_fma_f32 / v_pk_mul_f32 via ext_vector
//      float2). The pipeline is naturally pair-structured: (p,t) in W,
//      (s0,s1)/(s2,s3) SoA in H and D. Static VALU/plane ~420 -> ~275.
//      Hypothesis test: CDNA4 full-rate packed FP32 (CDNA2/3 had it).
//      Null result => pk not doubled on gfx950, pivot to stall structure.
//      Everything else identical to v15 (f32 SoA interm, BAR_LDS, layout).

#define D_DIM 64
#define H_DIM 192
#define W_DIM 192
#define SLICE (H_DIM * W_DIM)   // 36864
#define VOL   (D_DIM * SLICE)   // 2359296
#define NB    4
#define KS    11
#define RAD   5
#define TIL   16                // output tile 16x16
#define HLO   26                // halo extent
#define SROWS 32                // padded stage rows (2 uniform W tasks/thread)
#define SP2   28                // f32x2 staging pitch
#define IPP   17                // interm pitch (elements) per row
#define C1F   (0.01f * 0.01f)
#define C2F   (0.03f * 0.03f)

typedef float f32x2 __attribute__((ext_vector_type(2)));

// LDS-only barrier: order LDS ops, leave global loads (vmcnt) in flight.
#define BAR_LDS() do {                                                    \
    asm volatile("s_waitcnt lgkmcnt(0)" ::: "memory");                    \
    __builtin_amdgcn_s_barrier();                                         \
    __builtin_amdgcn_sched_barrier(0);                                    \
} while (0)

__device__ __forceinline__ void make_window(float* g) {
    float s = 0.f;
#pragma unroll
    for (int i = 0; i < KS; ++i) {
        float c = (float)(i - RAD);
        g[i] = expf(-(c * c) * (1.0f / 4.5f));  // 2*sigma^2 = 4.5
        s += g[i];
    }
    float inv = 1.0f / s;
#pragma unroll
    for (int i = 0; i < KS; ++i) g[i] *= inv;
}

#define SSIM_ACC(MP, MT, E2, T2, PT) do {                                 \
    float _mps = (MP) * (MP), _mts = (MT) * (MT), _mpt = (MP) * (MT);     \
    float _num = (2.f * _mpt + C1F) * (2.f * ((PT) - _mpt) + C2F);        \
    float _den = (_mps + _mts + C1F) *                                    \
                 (((E2) - _mps) + ((T2) - _mts) + C2F);                   \
    ssim_sum += _num * __builtin_amdgcn_rcpf(_den);                       \
} while (0)

__global__ __launch_bounds__(256) void fused_ssim_kernel(
    const float* __restrict__ pred, const float* __restrict__ targ,
    float* __restrict__ partials) {
    __shared__ f32x2 spt[SROWS * SP2];               // 7168 B
    __shared__ f32x2 i01[SROWS * IPP];               // 4352 B
    __shared__ f32x2 i23[SROWS * IPP];               // 4352 B
    __shared__ float i4 [SROWS * IPP];               // 2176 B
    __shared__ float red[4];

    float g[KS];
    make_window(g);

    const int tid = threadIdx.x;
    const int h0 = (blockIdx.x / 12) * TIL;
    const int w0 = (blockIdx.x % 12) * TIL;
    const int half = blockIdx.y;
    const float* pb = pred + (size_t)blockIdx.z * VOL;
    const float* tb = targ + (size_t)blockIdx.z * VOL;
    const int q0 = half ? 27 : 0;                    // first plane
    const int q1 = half ? 63 : 36;                   // last plane (incl)
    const int d_lo = half ? 32 : 0;
    const int d_hi = half ? 63 : 31;

    // ---- zero pad rows 26..31 of stage (read by W, never written) ----
    for (int i = HLO * SP2 + tid; i < SROWS * SP2; i += 256)
        spt[i] = (f32x2){0.f, 0.f};
    // (visibility to W ordered by the loop's first barrier)

    // ---- plane-invariant staging precompute (676 halo px, 3 strides) ----
    int sidx[3], slds[3];
    bool sa[3], sv[3];
#pragma unroll
    for (int k = 0; k < 3; ++k) {
        int i = tid + 256 * k;
        sa[k] = i < HLO * HLO;
        int y = i / HLO, x = i - y * HLO;
        int gh = h0 + y - RAD, gw = w0 + x - RAD;
        sv[k] = sa[k] && (unsigned)gh < (unsigned)H_DIM &&
                (unsigned)gw < (unsigned)W_DIM;
        sidx[k] = gh * W_DIM + gw;
        slds[k] = y * SP2 + x;
    }
    const int py = tid >> 4, px = tid & 15;          // H-phase pixel

    // ---- D-window accumulators: slot j = output d = q + j - 5 ----
    f32x2 a01[KS], a23[KS];
    float a4[KS];
#pragma unroll
    for (int j = 0; j < KS; ++j) {
        a01[j] = (f32x2){0.f, 0.f};
        a23[j] = (f32x2){0.f, 0.f};
        a4[j] = 0.f;
    }
    float ssim_sum = 0.f;

    // prologue: load plane q0 into regs
    float rp[3], rt[3];
    {
        const float* pq = pb + q0 * SLICE;
        const float* tq = tb + q0 * SLICE;
#pragma unroll
        for (int k = 0; k < 3; ++k) {
            rp[k] = sv[k] ? pq[sidx[k]] : 0.f;
            rt[k] = sv[k] ? tq[sidx[k]] : 0.f;
        }
    }

    for (int q = q0;; ++q) {
        // commit staged regs -> LDS (vmcnt auto-wait lands here, one full
        // plane after issue; WAR vs W(q-1) ordered by barrier2(q-1))
#pragma unroll
        for (int k = 0; k < 3; ++k)
            if (sa[k]) spt[slds[k]] = (f32x2){rp[k], rt[k]};
        // prefetch next plane; stays in flight across both barriers
        if (q < q1) {
            const float* pn = pb + (q + 1) * SLICE;
            const float* tn = tb + (q + 1) * SLICE;
#pragma unroll
            for (int k = 0; k < 3; ++k) {
                rp[k] = sv[k] ? pn[sidx[k]] : 0.f;
                rt[k] = sv[k] ? tn[sidx[k]] : 0.f;
            }
        }
        BAR_LDS();                                   // stage visible; H(q-1) done

        // ---- W phase: 512 uniform tasks (32 rows x 16 cols), pk-f32 ----
#pragma unroll
        for (int it = 0; it < 2; ++it) {
            int t = tid + it * 256;                  // 0..511, all valid
            int r = t >> 4, c = t & 15;
            const f32x2* pr = spt + r * SP2 + c;
            f32x2 s01 = (f32x2){0.f, 0.f};
            f32x2 s23 = (f32x2){0.f, 0.f};
            float s4 = 0.f;
#pragma unroll
            for (int k = 0; k < KS; ++k) {
                f32x2 v = pr[k];                     // ds_read_b64
                float gk = g[k];
                f32x2 gk2 = (f32x2){gk, gk};
                s01 += gk2 * v;                      // v_pk_fma_f32
                s23 += gk2 * (v * v);                // v_pk_mul + v_pk_fma
                s4 += gk * (v.x * v.y);              // v_mul + v_fma
            }
            int oi = r * IPP + c;
            i01[oi] = s01;                           // ds_write_b64
            i23[oi] = s23;                           // ds_write_b64
            i4 [oi] = s4;                            // ds_write_b32
        }
        BAR_LDS();                                   // interm visible

        // ---- H phase (pk-f32) + D accumulate + emit ----
        {
            const f32x2* c01 = i01 + px;
            const f32x2* c23 = i23 + px;
            const float* c4  = i4  + px;
            f32x2 v01 = (f32x2){0.f, 0.f};
            f32x2 v23 = (f32x2){0.f, 0.f};
            float v4 = 0.f;
#pragma unroll
            for (int k = 0; k < KS; ++k) {
                int rr = (py + k) * IPP;
                float gk = g[k];
                f32x2 gk2 = (f32x2){gk, gk};
                v01 += gk2 * c01[rr];                // ds_read_b64 + pk_fma
                v23 += gk2 * c23[rr];                // ds_read_b64 + pk_fma
                v4 += gk * c4[rr];                   // ds_read_b32 + fma
            }
            // plane q contributes g[10-j] to output d = q + j - 5
#pragma unroll
            for (int j = 0; j < KS; ++j) {
                float wj = g[10 - j];
                f32x2 wj2 = (f32x2){wj, wj};
                a01[j] += wj2 * v01;
                a23[j] += wj2 * v23;
                a4[j] += wj * v4;
            }
            if (q - 5 >= d_lo)                       // d = q-5 complete
                SSIM_ACC(a01[0].x, a01[0].y, a23[0].x, a23[0].y, a4[0]);
            // shift window down (compile-time indices -> registers)
#pragma unroll
            for (int j = 0; j < KS - 1; ++j) {
                a01[j] = a01[j + 1]; a23[j] = a23[j + 1]; a4[j] = a4[j + 1];
            }
            a01[10] = (f32x2){0.f, 0.f};
            a23[10] = (f32x2){0.f, 0.f};
            a4[10] = 0.f;
        }
        if (q == q1) break;
    }

    // ---- tail: outputs d = q1-4 .. q1 (zero-padded D windows) ----
#pragma unroll
    for (int j = 0; j < 5; ++j) {
        int d = q1 - 4 + j;
        if (d >= d_lo && d <= d_hi)
            SSIM_ACC(a01[j].x, a01[j].y, a23[j].x, a23[j].y, a4[j]);
    }

    // ---- block reduction ----
    float a = ssim_sum;
#pragma unroll
    for (int off = 32; off > 0; off >>= 1) a += __shfl_down(a, off, 64);
    int lane = tid & 63, wv = tid >> 6;
    if (lane == 0) red[wv] = a;
    __syncthreads();
    if (tid == 0)
        partials[((blockIdx.z * 2 + blockIdx.y) * 144) + blockIdx.x] =
            red[0] + red[1] + red[2] + red[3];
}

// ---- final reduction ----
__global__ __launch_bounds__(256) void finalize_kernel(
    const float* __restrict__ partials, int n, float* __restrict__ out) {
    double a = 0.0;
    for (int i = threadIdx.x; i < n; i += 256) a += (double)partials[i];
#pragma unroll
    for (int off = 32; off > 0; off >>= 1) a += __shfl_down(a, off, 64);
    __shared__ double red[4];
    int lane = threadIdx.x & 63, wv = threadIdx.x >> 6;
    if (lane == 0) red[wv] = a;
    __syncthreads();
    if (threadIdx.x == 0) {
        double s = red[0] + red[1] + red[2] + red[3];
        out[0] = (float)(1.0 - s / (double)((long long)NB * VOL));
    }
}

extern "C" void kernel_launch(void* const* d_in, const int* in_sizes, int n_in,
                              void* d_out, int out_size, void* d_ws, size_t ws_size,
                              hipStream_t stream) {
    const float* pred = (const float*)d_in[0];
    const float* targ = (const float*)d_in[1];
    float* out = (float*)d_out;
    float* partials = (float*)d_ws;                  // NB*288 floats

    fused_ssim_kernel<<<dim3(144, 2, NB), 256, 0, stream>>>(pred, targ, partials);
    finalize_kernel<<<1, 256, 0, stream>>>(partials, NB * 288, out);
}